// Round 3
// baseline (132.095 us; speedup 1.0000x reference)
//
#include <hip/hip_runtime.h>

// Problem constants (reference: B=8, N=16384, F=128, P=28)
#define FDIM  128
#define PDIM  28
#define KPAD  896              // 28 p-steps * 32 padded q
#define MPTS  131072           // 8 * 16384 points

typedef _Float16 half8   __attribute__((ext_vector_type(8)));
typedef _Float16 half4v  __attribute__((ext_vector_type(4)));
typedef float    floatx4 __attribute__((ext_vector_type(4)));

// ---------------------------------------------------------------------------
// Prep: IF [F][28][28] fp32 -> IFt [F][KPAD] f16, k = p*32 + q, zero pad q>=28
// ---------------------------------------------------------------------------
__global__ __launch_bounds__(256) void prep_ift(const float* __restrict__ IF,
                                                _Float16* __restrict__ IFt) {
    int idx = blockIdx.x * 256 + threadIdx.x;     // 0 .. 128*896-1
    int f = idx / KPAD;
    int k = idx - f * KPAD;
    int p = k >> 5;
    int q = k & 31;
    float v = (q < PDIM) ? IF[f * (PDIM * PDIM) + p * PDIM + q] : 0.0f;
    IFt[idx] = (_Float16)v;
}

// ---------------------------------------------------------------------------
// Main: C[m,f] = sum_k W[m,k] * IFt[k,f],  W[m, p*32+q] = k0[m,p]*k1[m,q]
// Block: 128 points x 128 features; 4 waves each own a 32-feature strip
// (128x32 wave tile: 8 m-tiles x 2 n-tiles of mfma_f32_16x16x32_f16).
// B staged in double-buffered LDS (one barrier per K-step); global prefetch
// issued right after the barrier so the pre-s_barrier vmcnt drain is hidden
// behind the 16-MFMA body. A fragments = (register-hoisted k1) * k0 scalar.
// ---------------------------------------------------------------------------
__global__ __launch_bounds__(256, 3) void feats_kernel(
    const float* __restrict__ x,       // [MPTS][2]
    const float* __restrict__ sigma,   // [1] log lengthscale
    const _Float16* __restrict__ IFt,  // [FDIM][KPAD] f16
    float* __restrict__ out)           // [MPTS][FDIM]
{
    // k0: f16 stride 36 -> b64 read at byte m*72+g*8: banks 18m mod 32 cover
    //     all 32 banks across 16 m-rows; 4-quad same-addr broadcast free.
    // k1/bs: f16 stride 40 (80 B) -> rows 16B-aligned; worst 2-way alias (free).
    __shared__ _Float16               k0s[128 * 36];
    __shared__ __align__(16) _Float16 k1s[128 * 40];
    __shared__ __align__(16) _Float16 bs[2][128 * 40];   // double buffer, 10 KB each

    const int tid  = threadIdx.x;
    const int lane = tid & 63;
    const int wave = tid >> 6;          // feature strip: f in [wave*32, +32)
    const int ln15 = lane & 15;
    const int quad = lane >> 4;

    const float ls    = __expf(sigma[0]);
    const float inv   = 0.5f / (ls * ls);
    const float gstep = 0.998f / 27.0f;

    // ---- staging geometry: 512 16B chunks per K-step, 2 per thread ----
    const uint4* gI = (const uint4*)IFt;            // 8 f16 per uint4
    const int c0 = tid, c1 = tid + 256;
    const int f0 = c0 >> 2, cq0 = c0 & 3;
    const int f1 = c1 >> 2, cq1 = c1 & 3;
    const int bo0 = f0 * 40 + cq0 * 8;              // f16 offset inside a buffer
    const int bo1 = f1 * 40 + cq1 * 8;

    // stage K-step 0 into bs[0]
    {
        uint4 p0 = gI[f0 * 112 + cq0];
        uint4 p1 = gI[f1 * 112 + cq1];
        *(uint4*)&bs[0][bo0] = p0;
        *(uint4*)&bs[0][bo1] = p1;
    }

    // ---- prologue: build k0 (threads 0..127) and k1 (threads 128..255) ----
    {
        const int ptl = tid & 127;
        const int ptg = blockIdx.x * 128 + ptl;
        if (tid < 128) {
            const float x0 = x[2 * ptg + 0];
            #pragma unroll
            for (int p = 0; p < PDIM; p++) {
                float d = (0.001f + p * gstep) - x0;
                k0s[ptl * 36 + p] = (_Float16)__expf(-inv * d * d);
            }
        } else {
            const float x1 = x[2 * ptg + 1];
            #pragma unroll
            for (int q = 0; q < PDIM; q++) {
                float d = (0.001f + q * gstep) - x1;
                k1s[ptl * 40 + q] = (_Float16)__expf(-inv * d * d);
            }
            #pragma unroll
            for (int q = PDIM; q < 32; q++)
                k1s[ptl * 40 + q] = (_Float16)0.0f;   // zero pad (quad 3 reads it)
        }
    }
    __syncthreads();

    // ---- hoisted k1 A-fragments: A[m=lane&15][k=quad*8+j], m-tile mt*16 ----
    half8 k1f[8];
    #pragma unroll
    for (int mt = 0; mt < 8; mt++)
        k1f[mt] = *(const half8*)&k1s[(mt * 16 + ln15) * 40 + quad * 8];

    floatx4 acc[8][2];
    #pragma unroll
    for (int mt = 0; mt < 8; mt++) {
        acc[mt][0] = (floatx4){0.0f, 0.0f, 0.0f, 0.0f};
        acc[mt][1] = (floatx4){0.0f, 0.0f, 0.0f, 0.0f};
    }

    const int nrow0 = (wave * 32 + ln15) * 40 + quad * 8;       // nt = 0
    const int nrow1 = (wave * 32 + 16 + ln15) * 40 + quad * 8;  // nt = 1

    // One K-step: prefetch next slice, 2 b128 bf reads, 8 af, 16 MFMA,
    // write prefetched slice to the other buffer, one barrier.
    #define KSTEP(J)                                                          \
    {                                                                         \
        const int kk = kk4 * 4 + (J);                                         \
        uint4 p0, p1;                                                         \
        if (kk < PDIM - 1) {                                                  \
            p0 = gI[f0 * 112 + (kk + 1) * 4 + cq0];                           \
            p1 = gI[f1 * 112 + (kk + 1) * 4 + cq1];                           \
        }                                                                     \
        const _Float16* buf = bs[kk & 1];                                     \
        half8 bf0 = *(const half8*)&buf[nrow0];                               \
        half8 bf1 = *(const half8*)&buf[nrow1];                               \
        _Pragma("unroll")                                                     \
        for (int mt = 0; mt < 8; mt++) {                                      \
            const half8 af = k1f[mt] * k0v[mt][(J)];                          \
            acc[mt][0] = __builtin_amdgcn_mfma_f32_16x16x32_f16(              \
                af, bf0, acc[mt][0], 0, 0, 0);                                \
            acc[mt][1] = __builtin_amdgcn_mfma_f32_16x16x32_f16(              \
                af, bf1, acc[mt][1], 0, 0, 0);                                \
        }                                                                     \
        if (kk < PDIM - 1) {                                                  \
            _Float16* nbuf = (_Float16*)bs[(kk + 1) & 1];                     \
            *(uint4*)&nbuf[bo0] = p0;                                         \
            *(uint4*)&nbuf[bo1] = p1;                                         \
            __syncthreads();                                                  \
        }                                                                     \
    }

    #pragma unroll 1
    for (int kk4 = 0; kk4 < 7; kk4++) {            // 7 groups of 4 K-steps
        half4v k0v[8];                              // k0[m][kk4*4 .. +3]
        #pragma unroll
        for (int mt = 0; mt < 8; mt++)
            k0v[mt] = *(const half4v*)&k0s[(mt * 16 + ln15) * 36 + kk4 * 4];
        KSTEP(0)
        KSTEP(1)
        KSTEP(2)
        KSTEP(3)
    }
    #undef KSTEP

    // ---- epilogue: C/D layout col = lane&15 (feature), row = quad*4 + r ----
    #pragma unroll
    for (int mt = 0; mt < 8; mt++) {
        const int row0 = blockIdx.x * 128 + mt * 16 + quad * 4;
        #pragma unroll
        for (int nt = 0; nt < 2; nt++) {
            const int col = wave * 32 + nt * 16 + ln15;
            float* op = out + (size_t)row0 * FDIM + col;
            #pragma unroll
            for (int r = 0; r < 4; r++)
                __builtin_nontemporal_store(acc[mt][nt][r], op + (size_t)r * FDIM);
        }
    }
}

// ---------------------------------------------------------------------------
extern "C" void kernel_launch(void* const* d_in, const int* in_sizes, int n_in,
                              void* d_out, int out_size, void* d_ws, size_t ws_size,
                              hipStream_t stream) {
    const float* x     = (const float*)d_in[0];   // [8,16384,2]
    const float* sigma = (const float*)d_in[1];   // [1]
    const float* IF    = (const float*)d_in[2];   // [128,28,28]
    float* out = (float*)d_out;                   // [8,16384,128] fp32

    // d_ws: IFt f16 [128][896] = 229376 bytes
    _Float16* IFt = (_Float16*)d_ws;

    prep_ift<<<(FDIM * KPAD) / 256, 256, 0, stream>>>(IF, IFt);          // 448 blocks
    feats_kernel<<<MPTS / 128, 256, 0, stream>>>(x, sigma, IFt, out);    // 1024 blocks
}

// Round 4
// 115.956 us; speedup vs baseline: 1.1392x; 1.1392x over previous
//
#include <hip/hip_runtime.h>

// Problem constants (reference: B=8, N=16384, F=128, P=28)
#define FDIM  128
#define PDIM  28
#define KPAD  896              // 28 p-steps * 32 padded q
#define MPTS  131072           // 8 * 16384 points
#define BSTR  904              // bs k-stride in f16 (896 + 8 pad; row = 1808 B, 16B-aligned)

typedef _Float16 half8   __attribute__((ext_vector_type(8)));
typedef _Float16 half4v  __attribute__((ext_vector_type(4)));
typedef float    floatx4 __attribute__((ext_vector_type(4)));

// ---------------------------------------------------------------------------
// Prep: IF [F][28][28] fp32 -> IFt [F][KPAD] f16, k = p*32 + q, zero pad q>=28
// ---------------------------------------------------------------------------
__global__ __launch_bounds__(256) void prep_ift(const float* __restrict__ IF,
                                                _Float16* __restrict__ IFt) {
    int idx = blockIdx.x * 256 + threadIdx.x;     // 0 .. 128*896-1
    int f = idx / KPAD;
    int k = idx - f * KPAD;
    int p = k >> 5;
    int q = k & 31;
    float v = (q < PDIM) ? IF[f * (PDIM * PDIM) + p * PDIM + q] : 0.0f;
    IFt[idx] = (_Float16)v;
}

// ---------------------------------------------------------------------------
// Main: C[m,f] = sum_k W[m,k] * IFt[k,f],  W[m, p*32+q] = k0[m,p]*k1[m,q]
// Persistent-B design: each block owns a 64-feature strip, stages ALL of it
// into LDS once (113 KB), then processes 8 chunks of 128 points. The K-loop
// has ZERO barriers and ZERO staging: 1 ds_read_b128 feeds 8 MFMAs.
// 256 blocks = 1 per CU (LDS-limited). Barriers: 2 per chunk (k0/k1 build).
// ---------------------------------------------------------------------------
__global__ __launch_bounds__(256, 1) void feats_kernel(
    const float* __restrict__ x,       // [MPTS][2]
    const float* __restrict__ sigma,   // [1] log lengthscale
    const _Float16* __restrict__ IFt,  // [FDIM][KPAD] f16
    float* __restrict__ out)           // [MPTS][FDIM]
{
    // bs: stride 904 f16 -> b128 start bank = 4*(ln15+quad) mod 32: 8 lanes per
    //     4-bank group = minimal 8-phase for a wave64 b128. 113 KB.
    // k0: f16 stride 36 -> b64 banks 18m mod 32 cover all 32 across 16 rows,
    //     quad broadcast free.  k1: stride 40, 16B-aligned rows, read 8x/chunk.
    __shared__ __align__(16) _Float16 bs[64 * BSTR];   // 115,712 B
    __shared__ _Float16               k0s[128 * 36];   //   9,216 B
    __shared__ __align__(16) _Float16 k1s[128 * 40];   //  10,240 B

    const int tid  = threadIdx.x;
    const int lane = tid & 63;
    const int wave = tid >> 6;          // wave's 16-feature sub-strip
    const int ln15 = lane & 15;
    const int quad = lane >> 4;

    const int fs    = blockIdx.x & 1;   // which 64-feature half
    const int mg    = blockIdx.x >> 1;  // 0..127: point group of 1024
    const int fbase = fs * 64;

    const float ls    = __expf(sigma[0]);
    const float inv   = 0.5f / (ls * ls);
    const float gstep = 0.998f / 27.0f;

    // ---- stage the whole B strip (64 f x 896 k) into LDS, once ----
    {
        const int row = tid >> 2;        // 0..63
        const int qtr = tid & 3;         // quarter of a 112-uint4 row
        const uint4* g = (const uint4*)(IFt + (size_t)(fbase + row) * KPAD) + qtr * 28;
        uint4* l = (uint4*)&bs[row * BSTR] + qtr * 28;
        #pragma unroll
        for (int j = 0; j < 28; j++)
            l[j] = g[j];
    }

    const int bfo = (wave * 16 + ln15) * BSTR + quad * 8;   // bf f16 offset base

    #pragma unroll 1
    for (int c = 0; c < 8; c++) {
        const int chunkbase = mg * 1024 + c * 128;

        __syncthreads();   // prev chunk's k0/k1 reads done (iter 0: B staged)

        // ---- build k0 (threads 0..127) and k1 (threads 128..255) ----
        {
            const int ptl = tid & 127;
            const int ptg = chunkbase + ptl;
            if (tid < 128) {
                const float x0 = x[2 * ptg + 0];
                #pragma unroll
                for (int p = 0; p < PDIM; p++) {
                    float d = (0.001f + p * gstep) - x0;
                    k0s[ptl * 36 + p] = (_Float16)__expf(-inv * d * d);
                }
            } else {
                const float x1 = x[2 * ptg + 1];
                #pragma unroll
                for (int q = 0; q < PDIM; q++) {
                    float d = (0.001f + q * gstep) - x1;
                    k1s[ptl * 40 + q] = (_Float16)__expf(-inv * d * d);
                }
                #pragma unroll
                for (int q = PDIM; q < 32; q++)
                    k1s[ptl * 40 + q] = (_Float16)0.0f;   // zero pad (quad 3)
            }
        }
        __syncthreads();

        // ---- hoisted k1 A-fragments: A[m=lane&15][k=quad*8+j] ----
        half8 k1f[8];
        #pragma unroll
        for (int mt = 0; mt < 8; mt++)
            k1f[mt] = *(const half8*)&k1s[(mt * 16 + ln15) * 40 + quad * 8];

        floatx4 acc[8];
        #pragma unroll
        for (int mt = 0; mt < 8; mt++)
            acc[mt] = (floatx4){0.0f, 0.0f, 0.0f, 0.0f};

        // ---- barrier-free K-loop: 28 steps, 1 b128 -> 8 MFMA each ----
        #pragma unroll 1
        for (int kk4 = 0; kk4 < 7; kk4++) {
            half4v k0v[8];                           // k0[m][kk4*4 .. +3]
            #pragma unroll
            for (int mt = 0; mt < 8; mt++)
                k0v[mt] = *(const half4v*)&k0s[(mt * 16 + ln15) * 36 + kk4 * 4];
            #pragma unroll
            for (int j = 0; j < 4; j++) {
                const half8 bf = *(const half8*)&bs[bfo + (kk4 * 4 + j) * 32];
                #pragma unroll
                for (int mt = 0; mt < 8; mt++) {
                    const half8 af = k1f[mt] * k0v[mt][j];
                    acc[mt] = __builtin_amdgcn_mfma_f32_16x16x32_f16(
                        af, bf, acc[mt], 0, 0, 0);
                }
            }
        }

        // ---- epilogue: col = lane&15 (feature), row = quad*4 + r ----
        const int col = fbase + wave * 16 + ln15;
        #pragma unroll
        for (int mt = 0; mt < 8; mt++) {
            const int row0 = chunkbase + mt * 16 + quad * 4;
            float* op = out + (size_t)row0 * FDIM + col;
            #pragma unroll
            for (int r = 0; r < 4; r++)
                __builtin_nontemporal_store(acc[mt][r], op + (size_t)r * FDIM);
        }
    }
}

// ---------------------------------------------------------------------------
extern "C" void kernel_launch(void* const* d_in, const int* in_sizes, int n_in,
                              void* d_out, int out_size, void* d_ws, size_t ws_size,
                              hipStream_t stream) {
    const float* x     = (const float*)d_in[0];   // [8,16384,2]
    const float* sigma = (const float*)d_in[1];   // [1]
    const float* IF    = (const float*)d_in[2];   // [128,28,28]
    float* out = (float*)d_out;                   // [8,16384,128] fp32

    // d_ws: IFt f16 [128][896] = 229,376 bytes
    _Float16* IFt = (_Float16*)d_ws;

    prep_ift<<<(FDIM * KPAD) / 256, 256, 0, stream>>>(IF, IFt);   // 448 blocks
    feats_kernel<<<256, 256, 0, stream>>>(x, sigma, IFt, out);    // 1 block/CU
}